// Round 7
// baseline (143.560 us; speedup 1.0000x reference)
//
#include <hip/hip_runtime.h>

#define DD 256
#define BB 8
#define SS 1024
#define XSTRIDE 264

typedef __attribute__((ext_vector_type(8))) short short8;
typedef __attribute__((ext_vector_type(4))) float float4v;

// round-to-nearest-even fp32 -> bf16 pair packed into u32 (a=low, b=high)
__device__ __forceinline__ unsigned bf16pair(float a, float b) {
    unsigned ua = __float_as_uint(a), ub = __float_as_uint(b);
    ua += 0x7FFFu + ((ua >> 16) & 1u);
    ub += 0x7FFFu + ((ub >> 16) & 1u);
    return (ua >> 16) | (ub & 0xFFFF0000u);
}
__device__ __forceinline__ unsigned short bf16one(float a) {
    unsigned ua = __float_as_uint(a);
    ua += 0x7FFFu + ((ua >> 16) & 1u);
    return (unsigned short)(ua >> 16);
}

// Block = 512 threads (8 waves), handles s0=2*bid and s0+1. Grid 512 = 2 blocks/CU.
// A rows r = sl*8+b (16). Wave w owns n-tiles 2w, 2w+1.
// Phase B: W_s B-frags generated in registers PAIRWISE (tiny live set -> no spill).
__global__ __launch_bounds__(512, 4)
void fused_hierddpm(const float* __restrict__ seq,
                    const float* __restrict__ M1, const float* __restrict__ P1,
                    const float* __restrict__ g1, const float* __restrict__ be1,
                    const float* __restrict__ M2, const float* __restrict__ P2,
                    const float* __restrict__ g2, const float* __restrict__ be2,
                    float* __restrict__ out)
{
    __shared__ float xs[2][BB][DD];                           // 16384 B residual fp32
    __shared__ __align__(16) unsigned short xsb[16][XSTRIDE]; // 8448 B input bf16 (A-layout)
    __shared__ __align__(16) unsigned short xtb[16][XSTRIDE]; // 8448 B LN'd xt bf16
    __shared__ float stats[8][16][2];                         // 1024 B

    const int tid  = threadIdx.x;
    const int w    = tid >> 6;
    const int lane = tid & 63;
    const int l15  = lane & 15;
    const int quad = lane >> 4;
    const int s0   = blockIdx.x * 2;
    const float k0 = (float)s0, k1 = (float)(s0 + 1);

    // ---- stage x into xs (fp32) and xsb (bf16 A-layout rows r = sl*8+b)
    {
        const float4* seq4 = (const float4*)seq;
        #pragma unroll
        for (int u = 0; u < 2; ++u) {
            int v  = tid + 512 * u;          // float4 index 0..1023
            int sl = v >> 9;
            int rm = v & 511;
            int b  = rm >> 6, j4 = rm & 63;
            float4 x = seq4[((size_t)b * SS + s0 + sl) * 64 + j4];
            ((float4*)xs)[v] = x;
            unsigned* dst = (unsigned*)&xsb[sl * 8 + b][4 * j4];
            dst[0] = bf16pair(x.x, x.y);
            dst[1] = bf16pair(x.z, x.w);
        }
    }
    __syncthreads();

    #pragma unroll 1
    for (int layer = 0; layer < 2; ++layer) {
        const float* M  = layer ? M2  : M1;
        const float* P  = layer ? P2  : P1;
        const float* g  = layer ? g2  : g1;
        const float* be = layer ? be2 : be1;

        // ======== phase A: xt = x @ M^T (MFMA); wave owns n-tiles 2w, 2w+1
        float4v acc1[2];
        acc1[0] = (float4v){0.f, 0.f, 0.f, 0.f};
        acc1[1] = (float4v){0.f, 0.f, 0.f, 0.f};

        #pragma unroll 1
        for (int kt = 0; kt < 8; ++kt) {
            short8 a = *(const short8*)&xsb[l15][kt * 32 + quad * 8];
            #pragma unroll
            for (int t = 0; t < 2; ++t) {
                int n0 = 16 * (2 * w + t);
                const float4* Mr = (const float4*)M +
                    ((size_t)(n0 + l15) * 64 + kt * 8 + quad * 2);
                float4 m0 = Mr[0], m1 = Mr[1];
                union { short8 s; unsigned u[4]; } bb;
                bb.u[0] = bf16pair(m0.x, m0.y);
                bb.u[1] = bf16pair(m0.z, m0.w);
                bb.u[2] = bf16pair(m1.x, m1.y);
                bb.u[3] = bf16pair(m1.z, m1.w);
                acc1[t] = __builtin_amdgcn_mfma_f32_16x16x32_bf16(a, bb.s, acc1[t], 0, 0, 0);
            }
        }

        // ======== LayerNorm in C-register layout (row m = quad*4+reg)
        {
            #pragma unroll
            for (int reg = 0; reg < 4; ++reg) {
                float sm = acc1[0][reg] + acc1[1][reg];
                float sq = fmaf(acc1[0][reg], acc1[0][reg], acc1[1][reg] * acc1[1][reg]);
                #pragma unroll
                for (int off = 1; off < 16; off <<= 1) {
                    sm += __shfl_xor(sm, off, 64);
                    sq += __shfl_xor(sq, off, 64);
                }
                if (l15 == 0) {
                    stats[w][quad * 4 + reg][0] = sm;
                    stats[w][quad * 4 + reg][1] = sq;
                }
            }
        }
        __syncthreads();
        {
            float mu[4], rs[4];
            #pragma unroll
            for (int reg = 0; reg < 4; ++reg) {
                int m = quad * 4 + reg;
                float sm = 0.f, sq = 0.f;
                #pragma unroll
                for (int ww = 0; ww < 8; ++ww) {
                    sm += stats[ww][m][0];
                    sq += stats[ww][m][1];
                }
                float mm = sm * (1.f / DD);
                mu[reg] = mm;
                rs[reg] = rsqrtf(sq * (1.f / DD) - mm * mm + 1e-5f);
            }
            #pragma unroll
            for (int t = 0; t < 2; ++t) {
                int col = 16 * (2 * w + t) + l15;
                float gv = g[col], bv = be[col];
                #pragma unroll
                for (int reg = 0; reg < 4; ++reg) {
                    float v = fmaf((acc1[t][reg] - mu[reg]) * rs[reg], gv, bv);
                    xtb[quad * 4 + reg][col] = bf16one(v);
                }
            }
        }
        __syncthreads();   // xtb ready for phase B

        // ======== phase B: Nk = xt @ W_s^T; B-frags generated pairwise in regs
        float4v accS[2][2];
        #pragma unroll
        for (int sl = 0; sl < 2; ++sl)
            #pragma unroll
            for (int t = 0; t < 2; ++t) accS[sl][t] = (float4v){0.f, 0.f, 0.f, 0.f};

        #pragma unroll 1
        for (int kt = 0; kt < 8; ++kt) {
            short8 a = *(const short8*)&xtb[l15][kt * 32 + quad * 8];
            #pragma unroll
            for (int t = 0; t < 2; ++t) {
                const int n = 16 * (2 * w + t) + l15;      // W row (output col i)
                const float* Pr = P + (size_t)n * DD + kt * 32 + quad * 8;
                float4 p0 = ((const float4*)Pr)[0];
                float4 p1 = ((const float4*)Pr)[1];
                const float pbase = (float)(n * DD + kt * 32 + quad * 8 + 2);
                union { short8 s; unsigned u[4]; } b0, b1;
                #pragma unroll
                for (int e = 0; e < 4; ++e) {
                    float pa = (e == 0) ? p0.x : (e == 1) ? p0.z : (e == 2) ? p1.x : p1.z;
                    float pb = (e == 0) ? p0.y : (e == 1) ? p0.w : (e == 2) ? p1.y : p1.w;
                    float ia = __builtin_amdgcn_rcpf(pbase + (float)(2 * e));
                    float ib = __builtin_amdgcn_rcpf(pbase + (float)(2 * e + 1));
                    float c0a = __builtin_amdgcn_cosf(__builtin_amdgcn_fractf(k0 * ia));
                    float c0b = __builtin_amdgcn_cosf(__builtin_amdgcn_fractf(k0 * ib));
                    b0.u[e] = bf16pair(pa * c0a, pb * c0b);
                    float c1a = __builtin_amdgcn_cosf(__builtin_amdgcn_fractf(k1 * ia));
                    float c1b = __builtin_amdgcn_cosf(__builtin_amdgcn_fractf(k1 * ib));
                    b1.u[e] = bf16pair(pa * c1a, pb * c1b);
                }
                accS[0][t] = __builtin_amdgcn_mfma_f32_16x16x32_bf16(a, b0.s, accS[0][t], 0, 0, 0);
                accS[1][t] = __builtin_amdgcn_mfma_f32_16x16x32_bf16(a, b1.s, accS[1][t], 0, 0, 0);
            }
        }

        // ======== epilogue: select valid s-half per quad, add residual
        #pragma unroll
        for (int t = 0; t < 2; ++t) {
            int col = 16 * (2 * w + t) + l15;
            float4v av = (quad < 2) ? accS[0][t] : accS[1][t];
            int sl = quad >> 1;
            #pragma unroll
            for (int reg = 0; reg < 4; ++reg) {
                int m = quad * 4 + reg;
                int b = m & 7;
                float val = av[reg] + xs[sl][b][col];
                if (layer == 0) {
                    xs[sl][b][col] = val;
                    xsb[m][col]    = bf16one(val);
                } else {
                    out[((size_t)b * SS + s0 + sl) * DD + col] = val;
                }
            }
        }
        if (layer == 0) __syncthreads();
    }
}

extern "C" void kernel_launch(void* const* d_in, const int* in_sizes, int n_in,
                              void* d_out, int out_size, void* d_ws, size_t ws_size,
                              hipStream_t stream)
{
    const float* seq = (const float*)d_in[0];
    const float* M1  = (const float*)d_in[1];
    const float* P1  = (const float*)d_in[2];
    const float* g1  = (const float*)d_in[3];
    const float* b1  = (const float*)d_in[4];
    const float* M2  = (const float*)d_in[5];
    const float* P2  = (const float*)d_in[6];
    const float* g2  = (const float*)d_in[7];
    const float* b2  = (const float*)d_in[8];
    float* out = (float*)d_out;

    fused_hierddpm<<<SS / 2, 512, 0, stream>>>(seq, M1, P1, g1, b1,
                                               M2, P2, g2, b2, out);
}

// Round 9
// 122.246 us; speedup vs baseline: 1.1744x; 1.1744x over previous
//
#include <hip/hip_runtime.h>

#define DD 256
#define BB 8
#define SS 1024
#define XSTRIDE 264   // f16 elems per LDS row (528 B, 16B-aligned, odd*16 banksplay)

typedef _Float16 half8  __attribute__((ext_vector_type(8)));
typedef _Float16 half2t __attribute__((ext_vector_type(2)));
typedef __fp16   fp16x2 __attribute__((ext_vector_type(2)));
typedef __attribute__((ext_vector_type(4))) float float4v;

__device__ __forceinline__ half2t pkrtz(float a, float b) {
    union { fp16x2 f; half2t h; } cv;
    cv.f = __builtin_amdgcn_cvt_pkrtz(a, b);
    return cv.h;
}

// one-shot cast of M1,P1,M2,P2 (each 256x256 f32) to f16 into ws.
// ws half-layout: [M1 | P1 | M2 | P2], 65536 halves each.
__global__ void cast_mats_f16(const float* __restrict__ M1, const float* __restrict__ P1,
                              const float* __restrict__ M2, const float* __restrict__ P2,
                              unsigned* __restrict__ ws)
{
    int id  = blockIdx.x * 256 + threadIdx.x;   // 0..131071 (u32 outputs)
    int mat = id >> 15;                          // 32768 u32 per matrix
    int off = id & 32767;
    const float2* src = (mat == 0) ? (const float2*)M1
                      : (mat == 1) ? (const float2*)P1
                      : (mat == 2) ? (const float2*)M2 : (const float2*)P2;
    float2 v = src[off];
    union { half2t h; unsigned u; } cv;
    cv.h = pkrtz(v.x, v.y);
    ws[id] = cv.u;
}

// Block = 512 threads (8 waves), s-pair (s0, s0+1) per block. Grid 512 = 2 blocks/CU.
// Wave w owns n-tiles 2w, 2w+1. A rows r = sl*8+b. Residual lives in registers.
template<bool PRECAST>
__global__ __launch_bounds__(512, 4)
void fused_hierddpm(const float* __restrict__ seq,
                    const float* __restrict__ M1, const float* __restrict__ P1,
                    const float* __restrict__ g1, const float* __restrict__ be1,
                    const float* __restrict__ M2, const float* __restrict__ P2,
                    const float* __restrict__ g2, const float* __restrict__ be2,
                    const _Float16* __restrict__ wsh,
                    float* __restrict__ out)
{
    __shared__ __align__(16) _Float16 xsb[16][XSTRIDE]; // input / layer-out, f16, A-layout
    __shared__ __align__(16) _Float16 xtb[16][XSTRIDE]; // LN'd xt, f16
    __shared__ float stats[8][16][2];

    const int tid  = threadIdx.x;
    const int w    = tid >> 6;
    const int lane = tid & 63;
    const int l15  = lane & 15;
    const int quad = lane >> 4;
    const int s0   = blockIdx.x * 2;
    const float k0 = (float)s0, k1 = (float)(s0 + 1);

    // ---- stage x into xsb (f16, rows r = sl*8+b), coalesced float4 reads
    {
        const float4* seq4 = (const float4*)seq;
        #pragma unroll
        for (int u = 0; u < 2; ++u) {
            int v  = tid + 512 * u;          // float4 index 0..1023
            int sl = v >> 9;
            int rm = v & 511;
            int b  = rm >> 6, j4 = rm & 63;
            float4 x = seq4[((size_t)b * SS + s0 + sl) * 64 + j4];
            half2t* dst = (half2t*)&xsb[sl * 8 + b][4 * j4];
            dst[0] = pkrtz(x.x, x.y);
            dst[1] = pkrtz(x.z, x.w);
        }
    }

    // ---- residual in registers: res[t][reg] for (sl=quad>>1, b=(quad*4+reg)&7)
    float res[2][4];
    {
        const int sl = quad >> 1;
        #pragma unroll
        for (int t = 0; t < 2; ++t) {
            int col = 16 * (2 * w + t) + l15;
            #pragma unroll
            for (int reg = 0; reg < 4; ++reg) {
                int b = (quad * 4 + reg) & 7;
                res[t][reg] = seq[((size_t)b * SS + s0 + sl) * DD + col];
            }
        }
    }
    __syncthreads();

    #pragma unroll 1
    for (int layer = 0; layer < 2; ++layer) {
        const float* M  = layer ? M2  : M1;
        const float* P  = layer ? P2  : P1;
        const float* g  = layer ? g2  : g1;
        const float* be = layer ? be2 : be1;
        const _Float16* Mh = wsh + (size_t)layer * 131072;
        const _Float16* Ph = Mh + 65536;

        // ======== phase A: xt = x @ M^T (f16 MFMA); wave owns n-tiles 2w,2w+1
        float4v acc1[2];
        acc1[0] = (float4v){0.f, 0.f, 0.f, 0.f};
        acc1[1] = (float4v){0.f, 0.f, 0.f, 0.f};

        #pragma unroll 1
        for (int kt = 0; kt < 8; ++kt) {
            half8 a = *(const half8*)&xsb[l15][kt * 32 + quad * 8];
            #pragma unroll
            for (int t = 0; t < 2; ++t) {
                int n = 16 * (2 * w + t) + l15;
                half8 bfrag;
                if (PRECAST) {
                    bfrag = *(const half8*)(Mh + (size_t)n * DD + kt * 32 + quad * 8);
                } else {
                    const float4* Mr = (const float4*)M +
                        ((size_t)n * 64 + kt * 8 + quad * 2);
                    float4 m0 = Mr[0], m1 = Mr[1];
                    union { half8 h; half2t h2[4]; } bb;
                    bb.h2[0] = pkrtz(m0.x, m0.y);
                    bb.h2[1] = pkrtz(m0.z, m0.w);
                    bb.h2[2] = pkrtz(m1.x, m1.y);
                    bb.h2[3] = pkrtz(m1.z, m1.w);
                    bfrag = bb.h;
                }
                acc1[t] = __builtin_amdgcn_mfma_f32_16x16x32_f16(a, bfrag, acc1[t], 0, 0, 0);
            }
        }

        // ======== LayerNorm in C-register layout (row m = quad*4+reg)
        {
            #pragma unroll
            for (int reg = 0; reg < 4; ++reg) {
                float sm = acc1[0][reg] + acc1[1][reg];
                float sq = fmaf(acc1[0][reg], acc1[0][reg], acc1[1][reg] * acc1[1][reg]);
                #pragma unroll
                for (int off = 1; off < 16; off <<= 1) {
                    sm += __shfl_xor(sm, off, 64);
                    sq += __shfl_xor(sq, off, 64);
                }
                if (l15 == 0) {
                    stats[w][quad * 4 + reg][0] = sm;
                    stats[w][quad * 4 + reg][1] = sq;
                }
            }
        }
        __syncthreads();
        {
            float mu[4], rs[4];
            #pragma unroll
            for (int reg = 0; reg < 4; ++reg) {
                int m = quad * 4 + reg;
                float sm = 0.f, sq = 0.f;
                #pragma unroll
                for (int ww = 0; ww < 8; ++ww) {
                    sm += stats[ww][m][0];
                    sq += stats[ww][m][1];
                }
                float mm = sm * (1.f / DD);
                mu[reg] = mm;
                rs[reg] = rsqrtf(sq * (1.f / DD) - mm * mm + 1e-5f);
            }
            #pragma unroll
            for (int t = 0; t < 2; ++t) {
                int col = 16 * (2 * w + t) + l15;
                float gv = g[col], bv = be[col];
                #pragma unroll
                for (int reg = 0; reg < 4; ++reg) {
                    float v = fmaf((acc1[t][reg] - mu[reg]) * rs[reg], gv, bv);
                    xtb[quad * 4 + reg][col] = (_Float16)v;
                }
            }
        }
        __syncthreads();   // xtb ready for phase B

        // ======== phase B: Nk = xt @ W_s^T; W = P * cos generated in regs (f16)
        float4v accS[2][2];
        #pragma unroll
        for (int sl = 0; sl < 2; ++sl)
            #pragma unroll
            for (int t = 0; t < 2; ++t) accS[sl][t] = (float4v){0.f, 0.f, 0.f, 0.f};

        #pragma unroll 1
        for (int kt = 0; kt < 8; ++kt) {
            half8 a = *(const half8*)&xtb[l15][kt * 32 + quad * 8];
            #pragma unroll
            for (int t = 0; t < 2; ++t) {
                const int n = 16 * (2 * w + t) + l15;      // W row (output col i)
                union { half8 h; half2t h2[4]; } pv;
                if (PRECAST) {
                    pv.h = *(const half8*)(Ph + (size_t)n * DD + kt * 32 + quad * 8);
                } else {
                    const float4* Pr = (const float4*)P +
                        ((size_t)n * 64 + kt * 8 + quad * 2);
                    float4 p0 = Pr[0], p1 = Pr[1];
                    pv.h2[0] = pkrtz(p0.x, p0.y);
                    pv.h2[1] = pkrtz(p0.z, p0.w);
                    pv.h2[2] = pkrtz(p1.x, p1.y);
                    pv.h2[3] = pkrtz(p1.z, p1.w);
                }
                const float pbase = (float)(n * DD + kt * 32 + quad * 8 + 2);
                union { half8 h; half2t h2[4]; } b0, b1;
                #pragma unroll
                for (int e = 0; e < 4; ++e) {
                    float ia = __builtin_amdgcn_rcpf(pbase + (float)(2 * e));
                    float ib = __builtin_amdgcn_rcpf(pbase + (float)(2 * e + 1));
                    half2t c0 = pkrtz(
                        __builtin_amdgcn_cosf(__builtin_amdgcn_fractf(k0 * ia)),
                        __builtin_amdgcn_cosf(__builtin_amdgcn_fractf(k0 * ib)));
                    half2t c1 = pkrtz(
                        __builtin_amdgcn_cosf(__builtin_amdgcn_fractf(k1 * ia)),
                        __builtin_amdgcn_cosf(__builtin_amdgcn_fractf(k1 * ib)));
                    b0.h2[e] = pv.h2[e] * c0;   // v_pk_mul_f16
                    b1.h2[e] = pv.h2[e] * c1;
                }
                accS[0][t] = __builtin_amdgcn_mfma_f32_16x16x32_f16(a, b0.h, accS[0][t], 0, 0, 0);
                accS[1][t] = __builtin_amdgcn_mfma_f32_16x16x32_f16(a, b1.h, accS[1][t], 0, 0, 0);
            }
        }

        // ======== epilogue: pick valid s-half per quad, add register residual
        #pragma unroll
        for (int t = 0; t < 2; ++t) {
            int col = 16 * (2 * w + t) + l15;
            float4v av = (quad < 2) ? accS[0][t] : accS[1][t];
            int sl = quad >> 1;
            #pragma unroll
            for (int reg = 0; reg < 4; ++reg) {
                int m = quad * 4 + reg;
                int b = m & 7;
                float val = av[reg] + res[t][reg];
                if (layer == 0) {
                    res[t][reg] = val;             // next layer's residual
                    xsb[m][col] = (_Float16)val;   // next layer's A-matrix
                } else {
                    out[((size_t)b * SS + s0 + sl) * DD + col] = val;
                }
            }
        }
        if (layer == 0) __syncthreads();
    }
}

extern "C" void kernel_launch(void* const* d_in, const int* in_sizes, int n_in,
                              void* d_out, int out_size, void* d_ws, size_t ws_size,
                              hipStream_t stream)
{
    const float* seq = (const float*)d_in[0];
    const float* M1  = (const float*)d_in[1];
    const float* P1  = (const float*)d_in[2];
    const float* g1  = (const float*)d_in[3];
    const float* b1  = (const float*)d_in[4];
    const float* M2  = (const float*)d_in[5];
    const float* P2  = (const float*)d_in[6];
    const float* g2  = (const float*)d_in[7];
    const float* b2  = (const float*)d_in[8];
    float* out = (float*)d_out;

    if (ws_size >= 512 * 1024) {
        cast_mats_f16<<<512, 256, 0, stream>>>(M1, P1, M2, P2, (unsigned*)d_ws);
        fused_hierddpm<true><<<SS / 2, 512, 0, stream>>>(
            seq, M1, P1, g1, b1, M2, P2, g2, b2, (const _Float16*)d_ws, out);
    } else {
        fused_hierddpm<false><<<SS / 2, 512, 0, stream>>>(
            seq, M1, P1, g1, b1, M2, P2, g2, b2, nullptr, out);
    }
}

// Round 10
// 114.412 us; speedup vs baseline: 1.2548x; 1.0685x over previous
//
#include <hip/hip_runtime.h>

#define DD 256
#define BB 8
#define SS 1024
#define XSTRIDE 264   // f16 elems per LDS row (528 B, 16B-aligned)

// ws layout per layer (bytes): Mtab 131072 | Ptab 131072 | Itab 262144 = 524288
#define LAYER_BYTES 524288
#define PTAB_OFF    131072
#define ITAB_OFF    262144
#define WS_NEEDED   (2 * LAYER_BYTES)

typedef _Float16 half8  __attribute__((ext_vector_type(8)));
typedef _Float16 half2t __attribute__((ext_vector_type(2)));
typedef __fp16   fp16x2 __attribute__((ext_vector_type(2)));
typedef __attribute__((ext_vector_type(4))) float float4v;

__device__ __forceinline__ half2t pkrtz(float a, float b) {
    union { fp16x2 f; half2t h; } cv;
    cv.f = __builtin_amdgcn_cvt_pkrtz(a, b);
    return cv.h;
}

// Build fragment-ordered tables: for gi = (kt*16 + (2w+t))*64 + lane,
// lane = quad*16 + l15, n = 16*(2w+t)+l15, j0 = kt*32+quad*8:
//   Mtab[gi] = M[n][j0..j0+7] (f16), Ptab[gi] = P[n][j0..j0+7] (f16),
//   Itab[gi] = 1/(n*256 + j0 + e + 2), e=0..7 (f32, two float4)
__global__ void build_tabs(const float* __restrict__ M1, const float* __restrict__ P1,
                           const float* __restrict__ M2, const float* __restrict__ P2,
                           char* __restrict__ ws)
{
    int gid   = blockIdx.x * 256 + threadIdx.x;   // 0..16383
    int layer = gid >> 13;
    int gi    = gid & 8191;                        // idx*64 + lane
    int idx   = gi >> 6;                           // 0..127 = kt*16 + wt
    int lane  = gi & 63;
    int kt    = idx >> 4;
    int wt    = idx & 15;
    int l15   = lane & 15, quad = lane >> 4;
    int n     = 16 * wt + l15;
    int j0    = kt * 32 + quad * 8;

    const float* Msrc = layer ? M2 : M1;
    const float* Psrc = layer ? P2 : P1;

    union { half8 h; half2t h2[4]; } mh, ph;
    float iv[8];
    #pragma unroll
    for (int e = 0; e < 4; ++e) {
        float ma = Msrc[(size_t)n * DD + j0 + 2 * e];
        float mb = Msrc[(size_t)n * DD + j0 + 2 * e + 1];
        float pa = Psrc[(size_t)n * DD + j0 + 2 * e];
        float pb = Psrc[(size_t)n * DD + j0 + 2 * e + 1];
        mh.h2[e] = pkrtz(ma, mb);
        ph.h2[e] = pkrtz(pa, pb);
        iv[2 * e]     = 1.0f / (float)(n * DD + j0 + 2 * e + 2);
        iv[2 * e + 1] = 1.0f / (float)(n * DD + j0 + 2 * e + 3);
    }
    char* base = ws + (size_t)layer * LAYER_BYTES;
    ((half8*)base)[gi]                       = mh.h;
    ((half8*)(base + PTAB_OFF))[gi]          = ph.h;
    float4* it = (float4*)(base + ITAB_OFF);
    it[2 * gi]     = make_float4(iv[0], iv[1], iv[2], iv[3]);
    it[2 * gi + 1] = make_float4(iv[4], iv[5], iv[6], iv[7]);
}

// Block = 512 threads (8 waves), s-pair (s0, s0+1) per block. Grid 512 = 2 blocks/CU.
// Wave w owns n-tiles 2w, 2w+1. A rows r = sl*8+b. Residual lives in registers.
// TABS: fragment-ordered f16/invp tables in ws (fully-coalesced hot-loop loads).
template<bool TABS>
__global__ __launch_bounds__(512, 4)
void fused_hierddpm(const float* __restrict__ seq,
                    const float* __restrict__ M1, const float* __restrict__ P1,
                    const float* __restrict__ g1, const float* __restrict__ be1,
                    const float* __restrict__ M2, const float* __restrict__ P2,
                    const float* __restrict__ g2, const float* __restrict__ be2,
                    const char* __restrict__ ws,
                    float* __restrict__ out)
{
    __shared__ __align__(16) _Float16 xsb[16][XSTRIDE]; // input / layer-out, f16, A-layout
    __shared__ __align__(16) _Float16 xtb[16][XSTRIDE]; // LN'd xt, f16
    __shared__ float stats[8][16][2];

    const int tid  = threadIdx.x;
    const int w    = tid >> 6;
    const int lane = tid & 63;
    const int l15  = lane & 15;
    const int quad = lane >> 4;
    const int s0   = blockIdx.x * 2;
    const float k0 = (float)s0, k1 = (float)(s0 + 1);

    // ---- stage x into xsb (f16, rows r = sl*8+b), coalesced float4 reads
    {
        const float4* seq4 = (const float4*)seq;
        #pragma unroll
        for (int u = 0; u < 2; ++u) {
            int v  = tid + 512 * u;          // float4 index 0..1023
            int sl = v >> 9;
            int rm = v & 511;
            int b  = rm >> 6, j4 = rm & 63;
            float4 x = seq4[((size_t)b * SS + s0 + sl) * 64 + j4];
            half2t* dst = (half2t*)&xsb[sl * 8 + b][4 * j4];
            dst[0] = pkrtz(x.x, x.y);
            dst[1] = pkrtz(x.z, x.w);
        }
    }

    // ---- residual in registers: res[t][reg] for (sl=quad>>1, b=(quad*4+reg)&7)
    float res[2][4];
    {
        const int sl = quad >> 1;
        #pragma unroll
        for (int t = 0; t < 2; ++t) {
            int col = 16 * (2 * w + t) + l15;
            #pragma unroll
            for (int reg = 0; reg < 4; ++reg) {
                int b = (quad * 4 + reg) & 7;
                res[t][reg] = seq[((size_t)b * SS + s0 + sl) * DD + col];
            }
        }
    }
    __syncthreads();

    #pragma unroll 1
    for (int layer = 0; layer < 2; ++layer) {
        const float* M  = layer ? M2  : M1;
        const float* P  = layer ? P2  : P1;
        const float* g  = layer ? g2  : g1;
        const float* be = layer ? be2 : be1;
        const char*  lbase = ws + (size_t)layer * LAYER_BYTES;
        const half8*  Mtab = (const half8*)lbase;
        const half8*  Ptab = (const half8*)(lbase + PTAB_OFF);
        const float4* Itab = (const float4*)(lbase + ITAB_OFF);

        // ======== phase A: xt = x @ M^T (f16 MFMA); wave owns n-tiles 2w,2w+1
        float4v acc1[2];
        acc1[0] = (float4v){0.f, 0.f, 0.f, 0.f};
        acc1[1] = (float4v){0.f, 0.f, 0.f, 0.f};

        #pragma unroll 1
        for (int kt = 0; kt < 8; ++kt) {
            half8 a = *(const half8*)&xsb[l15][kt * 32 + quad * 8];
            #pragma unroll
            for (int t = 0; t < 2; ++t) {
                half8 bfrag;
                if (TABS) {
                    bfrag = Mtab[(kt * 16 + 2 * w + t) * 64 + lane];
                } else {
                    int n = 16 * (2 * w + t) + l15;
                    const float4* Mr = (const float4*)M +
                        ((size_t)n * 64 + kt * 8 + quad * 2);
                    float4 m0 = Mr[0], m1 = Mr[1];
                    union { half8 h; half2t h2[4]; } bb;
                    bb.h2[0] = pkrtz(m0.x, m0.y);
                    bb.h2[1] = pkrtz(m0.z, m0.w);
                    bb.h2[2] = pkrtz(m1.x, m1.y);
                    bb.h2[3] = pkrtz(m1.z, m1.w);
                    bfrag = bb.h;
                }
                acc1[t] = __builtin_amdgcn_mfma_f32_16x16x32_f16(a, bfrag, acc1[t], 0, 0, 0);
            }
        }

        // ======== LayerNorm in C-register layout (row m = quad*4+reg)
        {
            #pragma unroll
            for (int reg = 0; reg < 4; ++reg) {
                float sm = acc1[0][reg] + acc1[1][reg];
                float sq = fmaf(acc1[0][reg], acc1[0][reg], acc1[1][reg] * acc1[1][reg]);
                #pragma unroll
                for (int off = 1; off < 16; off <<= 1) {
                    sm += __shfl_xor(sm, off, 64);
                    sq += __shfl_xor(sq, off, 64);
                }
                if (l15 == 0) {
                    stats[w][quad * 4 + reg][0] = sm;
                    stats[w][quad * 4 + reg][1] = sq;
                }
            }
        }
        __syncthreads();
        {
            float mu[4], rs[4];
            #pragma unroll
            for (int reg = 0; reg < 4; ++reg) {
                int m = quad * 4 + reg;
                float sm = 0.f, sq = 0.f;
                #pragma unroll
                for (int ww = 0; ww < 8; ++ww) {
                    sm += stats[ww][m][0];
                    sq += stats[ww][m][1];
                }
                float mm = sm * (1.f / DD);
                mu[reg] = mm;
                rs[reg] = rsqrtf(sq * (1.f / DD) - mm * mm + 1e-5f);
            }
            #pragma unroll
            for (int t = 0; t < 2; ++t) {
                int col = 16 * (2 * w + t) + l15;
                float gv = g[col], bv = be[col];
                #pragma unroll
                for (int reg = 0; reg < 4; ++reg) {
                    float v = fmaf((acc1[t][reg] - mu[reg]) * rs[reg], gv, bv);
                    xtb[quad * 4 + reg][col] = (_Float16)v;
                }
            }
        }
        __syncthreads();   // xtb ready for phase B

        // ======== phase B: Nk = xt @ W_s^T; W = P * cos generated in regs (f16)
        float4v accS[2][2];
        #pragma unroll
        for (int sl = 0; sl < 2; ++sl)
            #pragma unroll
            for (int t = 0; t < 2; ++t) accS[sl][t] = (float4v){0.f, 0.f, 0.f, 0.f};

        #pragma unroll 2
        for (int kt = 0; kt < 8; ++kt) {
            half8 a = *(const half8*)&xtb[l15][kt * 32 + quad * 8];
            #pragma unroll
            for (int t = 0; t < 2; ++t) {
                union { half8 h; half2t h2[4]; } pv;
                float iv[8];
                if (TABS) {
                    int gi = (kt * 16 + 2 * w + t) * 64 + lane;
                    pv.h = Ptab[gi];
                    float4 i0 = Itab[2 * gi], i1 = Itab[2 * gi + 1];
                    iv[0] = i0.x; iv[1] = i0.y; iv[2] = i0.z; iv[3] = i0.w;
                    iv[4] = i1.x; iv[5] = i1.y; iv[6] = i1.z; iv[7] = i1.w;
                } else {
                    int n = 16 * (2 * w + t) + l15;
                    const float4* Pr = (const float4*)P +
                        ((size_t)n * 64 + kt * 8 + quad * 2);
                    float4 p0 = Pr[0], p1 = Pr[1];
                    pv.h2[0] = pkrtz(p0.x, p0.y);
                    pv.h2[1] = pkrtz(p0.z, p0.w);
                    pv.h2[2] = pkrtz(p1.x, p1.y);
                    pv.h2[3] = pkrtz(p1.z, p1.w);
                    float pbase = (float)(n * DD + kt * 32 + quad * 8 + 2);
                    #pragma unroll
                    for (int e = 0; e < 8; ++e)
                        iv[e] = __builtin_amdgcn_rcpf(pbase + (float)e);
                }
                union { half8 h; half2t h2[4]; } b0, b1;
                #pragma unroll
                for (int e = 0; e < 4; ++e) {
                    float ia = iv[2 * e], ib = iv[2 * e + 1];
                    half2t c0 = pkrtz(
                        __builtin_amdgcn_cosf(__builtin_amdgcn_fractf(k0 * ia)),
                        __builtin_amdgcn_cosf(__builtin_amdgcn_fractf(k0 * ib)));
                    half2t c1 = pkrtz(
                        __builtin_amdgcn_cosf(__builtin_amdgcn_fractf(k1 * ia)),
                        __builtin_amdgcn_cosf(__builtin_amdgcn_fractf(k1 * ib)));
                    b0.h2[e] = pv.h2[e] * c0;   // v_pk_mul_f16
                    b1.h2[e] = pv.h2[e] * c1;
                }
                accS[0][t] = __builtin_amdgcn_mfma_f32_16x16x32_f16(a, b0.h, accS[0][t], 0, 0, 0);
                accS[1][t] = __builtin_amdgcn_mfma_f32_16x16x32_f16(a, b1.h, accS[1][t], 0, 0, 0);
            }
        }

        // ======== epilogue: pick valid s-half per quad, add register residual
        #pragma unroll
        for (int t = 0; t < 2; ++t) {
            int col = 16 * (2 * w + t) + l15;
            float4v av = (quad < 2) ? accS[0][t] : accS[1][t];
            int sl = quad >> 1;
            #pragma unroll
            for (int reg = 0; reg < 4; ++reg) {
                int m = quad * 4 + reg;
                int b = m & 7;
                float val = av[reg] + res[t][reg];
                if (layer == 0) {
                    res[t][reg] = val;             // next layer's residual
                    xsb[m][col] = (_Float16)val;   // next layer's A-matrix
                } else {
                    out[((size_t)b * SS + s0 + sl) * DD + col] = val;
                }
            }
        }
        if (layer == 0) __syncthreads();
    }
}

extern "C" void kernel_launch(void* const* d_in, const int* in_sizes, int n_in,
                              void* d_out, int out_size, void* d_ws, size_t ws_size,
                              hipStream_t stream)
{
    const float* seq = (const float*)d_in[0];
    const float* M1  = (const float*)d_in[1];
    const float* P1  = (const float*)d_in[2];
    const float* g1  = (const float*)d_in[3];
    const float* b1  = (const float*)d_in[4];
    const float* M2  = (const float*)d_in[5];
    const float* P2  = (const float*)d_in[6];
    const float* g2  = (const float*)d_in[7];
    const float* b2  = (const float*)d_in[8];
    float* out = (float*)d_out;

    if (ws_size >= WS_NEEDED) {
        build_tabs<<<64, 256, 0, stream>>>(M1, P1, M2, P2, (char*)d_ws);
        fused_hierddpm<true><<<SS / 2, 512, 0, stream>>>(
            seq, M1, P1, g1, b1, M2, P2, g2, b2, (const char*)d_ws, out);
    } else {
        fused_hierddpm<false><<<SS / 2, 512, 0, stream>>>(
            seq, M1, P1, g1, b1, M2, P2, g2, b2, nullptr, out);
    }
}